// Round 8
// baseline (179.278 us; speedup 1.0000x reference)
//
#include <hip/hip_runtime.h>
#include <math.h>

// Problem constants (from reference setup_inputs)
#define BB 8
#define CC 192
#define HH 128
#define WW 128
#define BANDR 32                    // rows per block (band)
#define NBANDS (HH / BANDR)         // 4 bands per image
#define NBLK  (BB * CC * NBANDS)    // 6144 blocks
#define LROWS (BANDR + 2)           // 34 LDS rows (band + top/bottom halo)

// R7 + amortization: same minimal inst/byte ratio (2.06 wave64-inst per KB
// of output; copy = 2.0), but 2x work per block: each thread owns TWO rows
// (lrow, lrow+16), so each wave has 2 independent loads in flight (2x MLP)
// and the barrier + launch + s_load overhead is amortized over 16KB out.

typedef float vf4 __attribute__((ext_vector_type(4)));

__device__ __forceinline__ float col9(float a0, float a1, float a2,
                                      float b0, float b1, float b2,
                                      float c0, float c1, float c2,
                                      float th, const float* kk) {
    float m;
    m = fmaf(th, kk[0], a0);
    m = fmaxf(m, fmaf(th, kk[1], a1));
    m = fmaxf(m, fmaf(th, kk[2], a2));
    m = fmaxf(m, fmaf(th, kk[3], b0));
    m = fmaxf(m, fmaf(th, kk[4], b1));
    m = fmaxf(m, fmaf(th, kk[5], b2));
    m = fmaxf(m, fmaf(th, kk[6], c0));
    m = fmaxf(m, fmaf(th, kk[7], c1));
    m = fmaxf(m, fmaf(th, kk[8], c2));
    return m;
}

__global__ __launch_bounds__(512) void dynmorph_kernel(
    const float* __restrict__ x,      // [B, C, H, W]
    const float* __restrict__ kern,   // [C, 9]
    const float* __restrict__ gw,     // [C]
    const float* __restrict__ gb,     // [C]
    float* __restrict__ out)          // [B, C, H, W]
{
    __shared__ float sm[LROWS * WW];  // 34 x 512B = 17408 B, linear

    const int tid  = threadIdx.x;     // 0..511
    const int wg   = tid & 31;        // column group within row
    const int col  = wg * 4;
    const int lrow = tid >> 5;        // local row 0..15 (also owns lrow+16)

    const int blk  = blockIdx.x;
    const int bc   = blk >> 2;        // image id = b*C + c (block-uniform)
    const int band = blk & 3;
    const int c    = bc % CC;
    const int r0   = band * BANDR;

    const float* xb = x   + (size_t)bc * (HH * WW);
    float*       ob = out + (size_t)bc * (HH * WW);

    // ---- Issue all global loads up front (2 independent per thread) ----
    const int gr0 = r0 + lrow;
    const int gr1 = r0 + lrow + 16;
    const vf4 Bv0 = *(const vf4*)(xb + gr0 * WW + col);
    const vf4 Bv1 = *(const vf4*)(xb + gr1 * WW + col);

    // Halo rows r0-1 / r0+32: one extra wave64 inst (wave 0 only).
    vf4 hv = (vf4)(0.0f);
    int hvalid = 0, hldsr = 0;
    if (tid < 64) {
        const int hrow = (tid < 32) ? (r0 - 1) : (r0 + BANDR);
        const int clmp = hrow < 0 ? 0 : (hrow > HH - 1 ? HH - 1 : hrow);
        hv     = *(const vf4*)(xb + clmp * WW + (tid & 31) * 4);
        hvalid = (hrow >= 0 && hrow < HH);
        hldsr  = (tid < 32) ? 0 : (LROWS - 1);
    }

    // Block-uniform coefficients (scalar loads; latency hidden by vmem)
    float kk[9];
#pragma unroll
    for (int q = 0; q < 9; ++q) kk[q] = kern[c * 9 + q];
    const float gwc = gw[c];
    const float gbc = gb[c];

    // ---- Stage to LDS (rows shifted +1: LDS row = local row + 1) ----
    *(vf4*)(&sm[(lrow + 1) * WW + col]) = Bv0;
    *(vf4*)(&sm[(lrow + 17) * WW + col]) = Bv1;
    if (tid < 64) {
        if (!hvalid) hv = (vf4)(0.0f);
        *(vf4*)(&sm[hldsr * WW + (tid & 31) * 4]) = hv;
    }
    __syncthreads();

    // ---- Compute both owned rows ----
#pragma unroll
    for (int h = 0; h < 2; ++h) {
        const int lr = lrow + h * 16;          // local row index of output
        const int gr = r0 + lr;
        const vf4 Bv = h ? Bv1 : Bv0;
        const vf4 A  = *(const vf4*)(&sm[lr * WW + col]);        // row gr-1
        const vf4 Cv = *(const vf4*)(&sm[(lr + 2) * WW + col]);  // row gr+1

        const float aL0 = __shfl_up(A.w, 1),  aR0 = __shfl_down(A.x, 1);
        const float bL0 = __shfl_up(Bv.w, 1), bR0 = __shfl_down(Bv.x, 1);
        const float cL0 = __shfl_up(Cv.w, 1), cR0 = __shfl_down(Cv.x, 1);
        const float aL = (wg == 0)  ? 0.0f : aL0;
        const float bL = (wg == 0)  ? 0.0f : bL0;
        const float cL = (wg == 0)  ? 0.0f : cL0;
        const float aR = (wg == 31) ? 0.0f : aR0;
        const float bR = (wg == 31) ? 0.0f : bR0;
        const float cR = (wg == 31) ? 0.0f : cR0;

        const float t0 = __builtin_amdgcn_rcpf(1.0f + __expf(-fmaf(Bv.x, gwc, gbc)));
        const float t1 = __builtin_amdgcn_rcpf(1.0f + __expf(-fmaf(Bv.y, gwc, gbc)));
        const float t2 = __builtin_amdgcn_rcpf(1.0f + __expf(-fmaf(Bv.z, gwc, gbc)));
        const float t3 = __builtin_amdgcn_rcpf(1.0f + __expf(-fmaf(Bv.w, gwc, gbc)));

        vf4 o;
        o.x = col9(aL,   A.x,  A.y,
                   bL,   Bv.x, Bv.y,
                   cL,   Cv.x, Cv.y, t0, kk);
        o.y = col9(A.x,  A.y,  A.z,
                   Bv.x, Bv.y, Bv.z,
                   Cv.x, Cv.y, Cv.z, t1, kk);
        o.z = col9(A.y,  A.z,  A.w,
                   Bv.y, Bv.z, Bv.w,
                   Cv.y, Cv.z, Cv.w, t2, kk);
        o.w = col9(A.z,  A.w,  aR,
                   Bv.z, Bv.w, bR,
                   Cv.z, Cv.w, cR, t3, kk);

        *(vf4*)(ob + gr * WW + col) = o;
    }
}

extern "C" void kernel_launch(void* const* d_in, const int* in_sizes, int n_in,
                              void* d_out, int out_size, void* d_ws, size_t ws_size,
                              hipStream_t stream) {
    const float* x    = (const float*)d_in[0];
    const float* kern = (const float*)d_in[1];
    const float* gw   = (const float*)d_in[2];
    const float* gb   = (const float*)d_in[3];
    float* out        = (float*)d_out;

    dim3 grid(NBLK);     // 6144 blocks; 24 queued/CU, 4 resident (32 wave slots)
    dim3 block(512);     // 8 waves
    dynmorph_kernel<<<grid, block, 0, stream>>>(x, kern, gw, gb, out);
}